// Round 1
// 580.984 us; speedup vs baseline: 1.0555x; 1.0555x over previous
//
#include <hip/hip_runtime.h>
#include <cstdint>
#include <cstddef>

typedef unsigned short u16;
typedef __bf16 bf16x8 __attribute__((ext_vector_type(8)));
typedef float f32x4 __attribute__((ext_vector_type(4)));

// ---------- helpers ----------
__device__ __forceinline__ u16 f2bf(float f) {            // round-to-nearest-even
  unsigned u = __float_as_uint(f);
  u += 0x7fffu + ((u >> 16) & 1u);
  return (u16)(u >> 16);
}

__device__ __forceinline__ float block_sum(float v, float* sbuf, int tid) {
#pragma unroll
  for (int off = 1; off < 64; off <<= 1) v += __shfl_xor(v, off, 64);
  if ((tid & 63) == 0) sbuf[tid >> 6] = v;
  __syncthreads();
  v = sbuf[0] + sbuf[1] + sbuf[2] + sbuf[3];
  __syncthreads();
  return v;
}

// async global->LDS, 16B per lane; LDS dest = wave-uniform base + lane*16.
__device__ __forceinline__ void gld16(const void* g, void* l) {
  __builtin_amdgcn_global_load_lds((const __attribute__((address_space(1))) void*)g,
                                   (__attribute__((address_space(3))) void*)l,
                                   16, 0, 0);
}

// XCD-aware tile swizzle (requires gridDim.x % 8 == 0).
__device__ __forceinline__ void swz(int& bx, int& by) {
  const int gx = gridDim.x, gy = gridDim.y;
  const int id = blockIdx.y * gx + blockIdx.x;
  const int xcd = id & 7, slot = id >> 3;
  bx = xcd * (gx >> 3) + slot / gy;
  by = slot % gy;
}

// Tiled K layout: kt[z][tile][c=d/8][t=0..127][j=d%8]  (16KB/tile, MFMA B-frag image)
// Tiled V layout: vt[z][tile][tc=t/8][d=0..63][j=t%8]  (16KB/tile)

// ---------- double-buffered GEMM K-loop (128x128 tile, BK=32) ----------
// Used by the split-K GEMMs (N=1024). AITER-style counted vmcnt, raw s_barrier.
#define GEMM_SETUP(Kdim)                                                         \
  const int lane = tid & 63, wave = tid >> 6;                                    \
  const int l15 = lane & 15, g = (lane >> 4) & 3;                                \
  const int wm = (wave >> 1) * 64, wn = (wave & 1) * 64;                         \
  const int c0 = tid, c1 = tid + 256;                                            \
  const int ar0 = c0 >> 2, ak0 = (c0 & 3) * 8;                                   \
  const int ar1 = c1 >> 2, ak1 = (c1 & 3) * 8;                                   \
  const size_t aoff0 = (size_t)(m0 + ar0) * Kdim + ak0;                          \
  const size_t aoff1 = (size_t)(m0 + ar1) * Kdim + ak1;                          \
  const size_t boff0 = (size_t)(n0 + ar0) * Kdim + ak0;                          \
  const size_t boff1 = (size_t)(n0 + ar1) * Kdim + ak1;

#define GEMM_STAGE(Aptr, Bptr, kk, buf)                                          \
    gld16(Aptr + aoff0 + (kk), As + (buf) * 4096 + (size_t)c0 * 8);              \
    gld16(Aptr + aoff1 + (kk), As + (buf) * 4096 + (size_t)c1 * 8);              \
    gld16(Bptr + boff0 + (kk), Bs + (buf) * 4096 + (size_t)c0 * 8);              \
    gld16(Bptr + boff1 + (kk), Bs + (buf) * 4096 + (size_t)c1 * 8);

#define GEMM_COMPUTE(buf)                                                        \
    { bf16x8 af[4], bg[4];                                                       \
      _Pragma("unroll")                                                          \
      for (int i = 0; i < 4; i++) {                                              \
        af[i] = *(const bf16x8*)(As + (buf) * 4096 + (wm + i * 16 + l15) * 32 + g * 8); \
        bg[i] = *(const bf16x8*)(Bs + (buf) * 4096 + (wn + i * 16 + l15) * 32 + g * 8); \
      }                                                                          \
      _Pragma("unroll")                                                          \
      for (int i = 0; i < 4; i++)                                                \
        _Pragma("unroll")                                                        \
        for (int j = 0; j < 4; j++)                                              \
          acc[i][j] = __builtin_amdgcn_mfma_f32_16x16x32_bf16(af[i], bg[j], acc[i][j], 0, 0, 0); }

#define GEMM_BODY_DB(Aptr, Bptr, Kdim)                                           \
  GEMM_SETUP(Kdim)                                                               \
  f32x4 acc[4][4] = {};                                                          \
  GEMM_STAGE(Aptr, Bptr, kstart, 0)                                              \
  int cur = 0;                                                                   \
  for (int k0 = kstart; k0 + 32 < kend; k0 += 32) {                              \
    GEMM_STAGE(Aptr, Bptr, k0 + 32, cur ^ 1)                                     \
    asm volatile("s_waitcnt vmcnt(4)\ns_barrier" ::: "memory");                  \
    GEMM_COMPUTE(cur)                                                            \
    asm volatile("s_waitcnt lgkmcnt(0)\ns_barrier" ::: "memory");                \
    cur ^= 1;                                                                    \
  }                                                                              \
  asm volatile("s_waitcnt vmcnt(0)\ns_barrier" ::: "memory");                    \
  GEMM_COMPUTE(cur)

// ---------- big-tile GEMM: BMx256 tile, BK=64, 512 threads (8 waves, 2Mx4N) ----------
// 2-phase double-buffered schedule (measured ~655-682 TF @ K=1024 regime, m230/m248),
// T2-correct LDS XOR swizzle: linear gld16 dest + inverse-swizzled GLOBAL source
// (chunk ^= row&7) + swizzled ds_read_b128 -> even bank load (16-way -> 2-way).
// MODE 0: bias+GELU -> bf16 out0[gm*N+col]
// MODE 1: qkv scatter -> qh(out0, *0.125), kt(out1), vt(out2)
// MODE 3: kv scatter  -> kt(out1), vt(out2)
template<int BM, int MODE>
__global__ __launch_bounds__(512, 2) void gemm_big(
    const u16* __restrict__ A, const u16* __restrict__ B,
    const float* __restrict__ bias,
    u16* __restrict__ out0, u16* __restrict__ out1, u16* __restrict__ out2,
    int N, int K)
{
  constexpr int NQA = BM / 64;        // gld16 per thread for A-tile
  constexpr int IF  = BM / 32;        // 16-row frags per wave (BM/2/16): 8 or 4
  __shared__ __align__(16) u16 As[2 * BM * 64];
  __shared__ __align__(16) u16 Bs[2 * 256 * 64];

  const int tid = threadIdx.x;
  const int lane = tid & 63, wave = tid >> 6;
  const int l15 = lane & 15, g = (lane >> 4) & 3;
  const int wr = (wave >> 2) * (BM / 2), wc = (wave & 3) * 64;

  // bijective XCD swizzle (m204): works for any nwg
  const int gx = gridDim.x;
  const int nwg = gx * gridDim.y;
  const int id = blockIdx.y * gx + blockIdx.x;
  const int qq = nwg >> 3, rr = nwg & 7;
  const int xcd = id & 7, slot = id >> 3;
  const int sid = (xcd < rr ? xcd * (qq + 1) : rr * (qq + 1) + (xcd - rr) * qq) + slot;
  const int bx = sid % gx, by = sid / gx;
  const int m0 = by * BM, n0 = bx * 256;

  // staging addresses: LDS linear (row, chunk=c&7); global source chunk = (c&7)^(row&7)
  size_t aoff[NQA]; int adst[NQA];
  size_t boff[4];   int bdst[4];
#pragma unroll
  for (int q = 0; q < NQA; ++q) {
    const int c = tid + q * 512, row = c >> 3, ch = (c & 7) ^ (row & 7);
    aoff[q] = (size_t)(m0 + row) * K + ch * 8;
    adst[q] = c * 8;
  }
#pragma unroll
  for (int q = 0; q < 4; ++q) {
    const int c = tid + q * 512, row = c >> 3, ch = (c & 7) ^ (row & 7);
    boff[q] = (size_t)(n0 + row) * K + ch * 8;
    bdst[q] = c * 8;
  }

#define G2_STAGE(kk, buf)                                                        \
  {                                                                              \
    _Pragma("unroll")                                                            \
    for (int q = 0; q < NQA; ++q) gld16(A + aoff[q] + (kk), As + (buf) * (BM * 64) + adst[q]); \
    _Pragma("unroll")                                                            \
    for (int q = 0; q < 4; ++q)  gld16(B + boff[q] + (kk), Bs + (buf) * 16384 + bdst[q]); \
  }

#define G2_COMPUTE(buf)                                                          \
  {                                                                              \
    _Pragma("unroll")                                                            \
    for (int ks = 0; ks < 2; ++ks) {                                             \
      const int chR = (((ks * 4 + g) ^ (l15 & 7)) * 8);                          \
      bf16x8 af[IF], bg[4];                                                      \
      _Pragma("unroll")                                                          \
      for (int i = 0; i < IF; ++i)                                               \
        af[i] = *(const bf16x8*)(As + (buf) * (BM * 64) + (wr + i * 16 + l15) * 64 + chR); \
      _Pragma("unroll")                                                          \
      for (int j = 0; j < 4; ++j)                                                \
        bg[j] = *(const bf16x8*)(Bs + (buf) * 16384 + (wc + j * 16 + l15) * 64 + chR); \
      _Pragma("unroll")                                                          \
      for (int i = 0; i < IF; ++i)                                               \
        _Pragma("unroll")                                                        \
        for (int j = 0; j < 4; ++j)                                              \
          acc[i][j] = __builtin_amdgcn_mfma_f32_16x16x32_bf16(af[i], bg[j], acc[i][j], 0, 0, 0); \
    }                                                                            \
  }

  f32x4 acc[IF][4] = {};
  const int NT = K >> 6;
  G2_STAGE(0, 0)
  int cur = 0;
  for (int t = 0; t < NT - 1; ++t) {
    G2_STAGE((t + 1) * 64, cur ^ 1)
    if constexpr (BM == 256) asm volatile("s_waitcnt vmcnt(8)\ns_barrier" ::: "memory");
    else                     asm volatile("s_waitcnt vmcnt(6)\ns_barrier" ::: "memory");
    G2_COMPUTE(cur)
    asm volatile("s_waitcnt lgkmcnt(0)\ns_barrier" ::: "memory");
    cur ^= 1;
  }
  asm volatile("s_waitcnt vmcnt(0)\ns_barrier" ::: "memory");
  G2_COMPUTE(cur)

#undef G2_STAGE
#undef G2_COMPUTE

  if constexpr (MODE == 0) {
#pragma unroll
    for (int i = 0; i < IF; ++i) {
#pragma unroll
      for (int j = 0; j < 4; ++j) {
        const int col = n0 + wc + j * 16 + l15;
        const float bs = bias[col];
#pragma unroll
        for (int r = 0; r < 4; ++r) {
          const int gm = m0 + wr + i * 16 + g * 4 + r;
          float v = acc[i][j][r] + bs;
          v = 0.5f * v * (1.0f + erff(v * 0.70710678118654752f));
          out0[(size_t)gm * N + col] = f2bf(v);
        }
      }
    }
  } else {
#pragma unroll
    for (int i = 0; i < IF; ++i) {
#pragma unroll
      for (int j = 0; j < 4; ++j) {
        const int col = n0 + wc + j * 16 + l15;
        const int sec = (n0 + wc + j * 16) >> 10;          // wave-uniform section
        const int tgt = (MODE == 1) ? sec : sec + 1;
        const float bs = bias[col];
#pragma unroll
        for (int r = 0; r < 4; ++r) {
          const int gm = m0 + wr + i * 16 + g * 4 + r;
          const float v = acc[i][j][r] + bs;
          const int cl = col & 1023, h = cl >> 6, d = cl & 63;
          const int z = (gm >> 10) * 16 + h, s = gm & 1023;
          if (tgt == 0)
            out0[((size_t)z * 1024 + s) * 64 + d] = f2bf(v * 0.125f);
          else if (tgt == 1)
            out1[((((size_t)z * 8 + (s >> 7)) * 8 + (d >> 3)) * 128 + (s & 127)) * 8 + (d & 7)] = f2bf(v);
          else
            out2[((size_t)z * 8 + (s >> 7)) * 8192 + (((s >> 3) & 15) * 64 + d) * 8 + (s & 7)] = f2bf(v);
        }
      }
    }
  }
}

// ---------- split-K NT GEMM (M=4096, N=1024; fp32 partials [z][4096][1024]) ----------
__global__ __launch_bounds__(256) void gemm_splitk(
    const u16* __restrict__ A, const u16* __restrict__ B,
    float* __restrict__ part, int K, int Klen)
{
  __shared__ __align__(16) u16 As[2 * 128 * 32];
  __shared__ __align__(16) u16 Bs[2 * 128 * 32];
  const int tid = threadIdx.x;
  int bx, by; swz(bx, by);
  const int m0 = by * 128, n0 = bx * 128;
  const int kstart = blockIdx.z * Klen, kend = kstart + Klen;
  float* outP = part + (size_t)blockIdx.z * (4096ULL * 1024);
  GEMM_BODY_DB(A, B, K)

#pragma unroll
  for (int i = 0; i < 4; i++)
#pragma unroll
    for (int j = 0; j < 4; j++) {
      const int col = n0 + wn + j * 16 + l15;
#pragma unroll
      for (int r = 0; r < 4; r++) {
        const int gm = m0 + wm + i * 16 + g * 4 + r;
        outP[(size_t)gm * 1024 + col] = acc[i][j][r];
      }
    }
}

// ---------- flash attention v3 (proven) + head-per-XCD swizzle ----------
__global__ __launch_bounds__(256, 2) void flash_attn(
    const u16* __restrict__ qh, const u16* __restrict__ kt, const u16* __restrict__ vt,
    const float* __restrict__ emask, u16* __restrict__ ctx, int causal)
{
  __shared__ __align__(16) u16 sK[8192];
  __shared__ __align__(16) u16 sV[8192];
  __shared__ __align__(16) u16 sP[128 * 72];

  const int tid = threadIdx.x, lane = tid & 63, wave = tid >> 6;
  const int l15 = lane & 15, g = (lane >> 4) & 3;
  const int id = blockIdx.y * 8 + blockIdx.x;
  const int xcd = id & 7, slot = id >> 3;
  const int z = xcd * 8 + (slot >> 3), b = z >> 4, h = z & 15;
  const int m0 = (slot & 7) * 128;
  const int r0 = wave * 32;

  bf16x8 qf[2][2];
  {
    const u16* qz = qh + ((size_t)z * 1024 + m0 + r0 + l15) * 64 + g * 8;
#pragma unroll
    for (int i2 = 0; i2 < 2; ++i2)
#pragma unroll
      for (int kc = 0; kc < 2; ++kc)
        qf[i2][kc] = *(const bf16x8*)(qz + (size_t)i2 * 16 * 64 + kc * 32);
  }

  float m_i[2][4], l_i[2][4];
#pragma unroll
  for (int i2 = 0; i2 < 2; ++i2)
#pragma unroll
    for (int r = 0; r < 4; ++r) { m_i[i2][r] = -1.0e30f; l_i[i2][r] = 0.0f; }

  f32x4 o[2][4] = {};
  const int tmax = causal ? m0 : 896;

  for (int t0 = 0; t0 <= tmax; t0 += 128) {
    const u16* ktile = kt + ((size_t)z * 8 + (t0 >> 7)) * 8192;
    const u16* vtile = vt + ((size_t)z * 8 + (t0 >> 7)) * 8192;
    __syncthreads();
#pragma unroll
    for (int i = 0; i < 4; ++i) {
      const int off = (wave * 4 + i) * 512 + lane * 8;
      gld16(ktile + off, sK + off);
      gld16(vtile + off, sV + off);
    }
    __syncthreads();

#pragma unroll
    for (int ci = 0; ci < 2; ++ci) {
      if (causal && t0 == m0 && ci * 64 > r0 + 31) continue;

      f32x4 sa[2][4] = {};
#pragma unroll
      for (int kc = 0; kc < 2; ++kc) {
        bf16x8 bg[4];
#pragma unroll
        for (int jn = 0; jn < 4; ++jn)
          bg[jn] = *(const bf16x8*)(sK + ((kc * 4 + g) * 128 + ci * 64 + jn * 16 + l15) * 8);
#pragma unroll
        for (int i2 = 0; i2 < 2; ++i2)
#pragma unroll
          for (int jn = 0; jn < 4; ++jn)
            sa[i2][jn] = __builtin_amdgcn_mfma_f32_16x16x32_bf16(qf[i2][kc], bg[jn], sa[i2][jn], 0, 0, 0);
      }

      if (causal) {
        if (t0 == m0 && ci * 64 + 63 > r0) {
#pragma unroll
          for (int i2 = 0; i2 < 2; ++i2)
#pragma unroll
            for (int jn = 0; jn < 4; ++jn) {
              const int col = ci * 64 + jn * 16 + l15;
#pragma unroll
              for (int r = 0; r < 4; ++r) {
                const int row = r0 + i2 * 16 + g * 4 + r;
                if (col > row) sa[i2][jn][r] = -3.0e38f;
              }
            }
        }
      } else {
#pragma unroll
        for (int jn = 0; jn < 4; ++jn) {
          const float mv = emask[(size_t)b * 1024 + t0 + ci * 64 + jn * 16 + l15];
#pragma unroll
          for (int i2 = 0; i2 < 2; ++i2)
#pragma unroll
            for (int r = 0; r < 4; ++r) sa[i2][jn][r] += mv;
        }
      }

      float alpha[2][4];
#pragma unroll
      for (int i2 = 0; i2 < 2; ++i2)
#pragma unroll
        for (int r = 0; r < 4; ++r) {
          const int rowl = r0 + i2 * 16 + g * 4 + r;
          float v = fmaxf(fmaxf(sa[i2][0][r], sa[i2][1][r]), fmaxf(sa[i2][2][r], sa[i2][3][r]));
          v = fmaxf(v, __shfl_xor(v, 1, 64));
          v = fmaxf(v, __shfl_xor(v, 2, 64));
          v = fmaxf(v, __shfl_xor(v, 4, 64));
          v = fmaxf(v, __shfl_xor(v, 8, 64));
          const float mo = m_i[i2][r];
          const float mn = fmaxf(mo, v);
          m_i[i2][r] = mn;
          alpha[i2][r] = __expf(mo - mn);
          float s = 0.0f;
#pragma unroll
          for (int jn = 0; jn < 4; ++jn) {
            const float p = __expf(sa[i2][jn][r] - mn);
            s += p;
            sP[rowl * 72 + jn * 16 + l15] = f2bf(p);
          }
          s += __shfl_xor(s, 1, 64);
          s += __shfl_xor(s, 2, 64);
          s += __shfl_xor(s, 4, 64);
          s += __shfl_xor(s, 8, 64);
          l_i[i2][r] = alpha[i2][r] * l_i[i2][r] + s;
        }

#pragma unroll
      for (int i2 = 0; i2 < 2; ++i2)
#pragma unroll
        for (int jn = 0; jn < 4; ++jn)
#pragma unroll
          for (int r = 0; r < 4; ++r)
            o[i2][jn][r] *= alpha[i2][r];

      asm volatile("s_waitcnt lgkmcnt(0)" ::: "memory");
#pragma unroll
      for (int kc2 = 0; kc2 < 2; ++kc2) {
        bf16x8 pa[2], vb[4];
#pragma unroll
        for (int i2 = 0; i2 < 2; ++i2)
          pa[i2] = *(const bf16x8*)(sP + (r0 + i2 * 16 + l15) * 72 + kc2 * 32 + g * 8);
#pragma unroll
        for (int jn = 0; jn < 4; ++jn)
          vb[jn] = *(const bf16x8*)(sV + ((ci * 8 + kc2 * 4 + g) * 64 + jn * 16 + l15) * 8);
#pragma unroll
        for (int i2 = 0; i2 < 2; ++i2)
#pragma unroll
          for (int jn = 0; jn < 4; ++jn)
            o[i2][jn] = __builtin_amdgcn_mfma_f32_16x16x32_bf16(pa[i2], vb[jn], o[i2][jn], 0, 0, 0);
      }
    }
  }

#pragma unroll
  for (int i2 = 0; i2 < 2; ++i2)
#pragma unroll
    for (int r = 0; r < 4; ++r) {
      const float inv = 1.0f / l_i[i2][r];
      const size_t base = ((size_t)(b * 1024 + m0 + r0 + i2 * 16 + g * 4 + r)) * 1024 + h * 64;
#pragma unroll
      for (int jn = 0; jn < 4; ++jn)
        ctx[base + jn * 16 + l15] = f2bf(o[i2][jn][r] * inv);
    }
}

// ---------- mega prep: 7 weight transposes + enc cvt + LN1 in one launch ----------
struct PrepArgs {
  const float* w[7]; u16* wt[7]; int K[7]; int N[7]; int cum[7];
  const float* enc; u16* enc_bf;
  const float* hid; const float* ln1w; const float* ln1b; u16* xln;
};
__global__ __launch_bounds__(256) void prep_kernel(PrepArgs a) {
  __shared__ float t[32][33];
  __shared__ float sbuf[4];
  const int bb = blockIdx.x, tid = threadIdx.x;
  if (bb < 16384) {
    int wi = 0;
#pragma unroll
    for (int i = 0; i < 7; ++i) if (bb >= a.cum[i]) wi = i + 1; else break;
    const int base = wi ? a.cum[wi - 1] : 0;
    const int tileIdx = bb - base;
    const int Kd = a.K[wi], Nd = a.N[wi], nx = Nd >> 5;
    const int n0 = (tileIdx % nx) * 32, k0 = (tileIdx / nx) * 32;
    const float* w = a.w[wi]; u16* wt = a.wt[wi];
    const int tx = tid & 31, ty = tid >> 5;
#pragma unroll
    for (int r = ty; r < 32; r += 8) t[r][tx] = w[(size_t)(k0 + r) * Nd + n0 + tx];
    __syncthreads();
#pragma unroll
    for (int r = ty; r < 32; r += 8) wt[(size_t)(n0 + r) * Kd + k0 + tx] = f2bf(t[tx][r]);
  } else if (bb < 20480) {
    const size_t i = ((size_t)(bb - 16384) * 256 + tid) * 4;
    const float4 v = *(const float4*)(a.enc + i);
    ushort4 o; o.x = f2bf(v.x); o.y = f2bf(v.y); o.z = f2bf(v.z); o.w = f2bf(v.w);
    *(ushort4*)(a.enc_bf + i) = o;
  } else {
    const int row = bb - 20480;
    const float4 v = *(const float4*)(a.hid + (size_t)row * 1024 + tid * 4);
    float s = block_sum(v.x + v.y + v.z + v.w, sbuf, tid);
    const float u = s * (1.0f / 1024.0f);
    const float d0 = v.x - u, d1 = v.y - u, d2 = v.z - u, d3 = v.w - u;
    float sq = block_sum(d0 * d0 + d1 * d1 + d2 * d2 + d3 * d3, sbuf, tid);
    const float rstd = rsqrtf(sq * (1.0f / 1024.0f) + 1e-12f);
    const int c = tid * 4;
    ushort4 o;
    o.x = f2bf(a.ln1w[c + 0] * d0 * rstd + a.ln1b[c + 0]);
    o.y = f2bf(a.ln1w[c + 1] * d1 * rstd + a.ln1b[c + 1]);
    o.z = f2bf(a.ln1w[c + 2] * d2 * rstd + a.ln1b[c + 2]);
    o.w = f2bf(a.ln1w[c + 3] * d3 * rstd + a.ln1b[c + 3]);
    *(ushort4*)(a.xln + (size_t)row * 1024 + c) = o;
  }
}

// ---------- 2-way reducers ----------
__global__ __launch_bounds__(256) void ln_red_kernel(
    const float* __restrict__ p0, const float* __restrict__ p1,
    const float* __restrict__ bias, const float* __restrict__ res,
    const float* __restrict__ w, const float* __restrict__ b,
    float* __restrict__ hOut, u16* __restrict__ xln)
{
  __shared__ float sbuf[4];
  const int row = blockIdx.x, tid = threadIdx.x;
  const size_t off = (size_t)row * 1024 + tid * 4;
  const int c = tid * 4;
  const float4 a0 = *(const float4*)(p0 + off);
  const float4 a1 = *(const float4*)(p1 + off);
  const float4 bs = *(const float4*)(bias + c);
  const float4 rs = *(const float4*)(res + off);
  float4 v;
  v.x = a0.x + a1.x + bs.x + rs.x;
  v.y = a0.y + a1.y + bs.y + rs.y;
  v.z = a0.z + a1.z + bs.z + rs.z;
  v.w = a0.w + a1.w + bs.w + rs.w;
  *(float4*)(hOut + off) = v;
  float s = block_sum(v.x + v.y + v.z + v.w, sbuf, tid);
  const float u = s * (1.0f / 1024.0f);
  const float d0 = v.x - u, d1 = v.y - u, d2 = v.z - u, d3 = v.w - u;
  float sq = block_sum(d0 * d0 + d1 * d1 + d2 * d2 + d3 * d3, sbuf, tid);
  const float rstd = rsqrtf(sq * (1.0f / 1024.0f) + 1e-12f);
  ushort4 o;
  o.x = f2bf(w[c + 0] * d0 * rstd + b[c + 0]);
  o.y = f2bf(w[c + 1] * d1 * rstd + b[c + 1]);
  o.z = f2bf(w[c + 2] * d2 * rstd + b[c + 2]);
  o.w = f2bf(w[c + 3] * d3 * rstd + b[c + 3]);
  *(ushort4*)(xln + off) = o;
}

__global__ __launch_bounds__(256) void reduce_q_kernel(
    const float* __restrict__ p0, const float* __restrict__ p1,
    const float* __restrict__ bias, u16* __restrict__ qh)
{
  const int m = blockIdx.x, tid = threadIdx.x;
  const size_t off = (size_t)m * 1024 + tid * 4;
  const int n = tid * 4, h = n >> 6, d = n & 63;
  const int b = m >> 10, s = m & 1023;
  const float4 a0 = *(const float4*)(p0 + off);
  const float4 a1 = *(const float4*)(p1 + off);
  const float4 bs = *(const float4*)(bias + n);
  ushort4 o;
  o.x = f2bf((a0.x + a1.x + bs.x) * 0.125f);
  o.y = f2bf((a0.y + a1.y + bs.y) * 0.125f);
  o.z = f2bf((a0.z + a1.z + bs.z) * 0.125f);
  o.w = f2bf((a0.w + a1.w + bs.w) * 0.125f);
  *(ushort4*)(qh + ((size_t)((b * 16 + h) * 1024 + s)) * 64 + d) = o;
}

__global__ __launch_bounds__(256) void reduce_out_kernel(
    const float* __restrict__ p0, const float* __restrict__ p1,
    const float* __restrict__ bias, const float* __restrict__ res,
    float* __restrict__ out)
{
  const int m = blockIdx.x, tid = threadIdx.x;
  const size_t off = (size_t)m * 1024 + tid * 4;
  const int c = tid * 4;
  const float4 a0 = *(const float4*)(p0 + off);
  const float4 a1 = *(const float4*)(p1 + off);
  const float4 bs = *(const float4*)(bias + c);
  const float4 rs = *(const float4*)(res + off);
  float4 v;
  v.x = a0.x + a1.x + bs.x + rs.x;
  v.y = a0.y + a1.y + bs.y + rs.y;
  v.z = a0.z + a1.z + bs.z + rs.z;
  v.w = a0.w + a1.w + bs.w + rs.w;
  *(float4*)(out + off) = v;
}

// ---------- workspace layout (bytes) ----------
constexpr size_t MB = 1024ULL * 1024;
constexpr size_t WT_QKV    = 0;            // 6 MB
constexpr size_t WT_ATTN_O = 6 * MB;       // 2
constexpr size_t WT_Q      = 8 * MB;       // 2
constexpr size_t WT_KV     = 10 * MB;      // 4
constexpr size_t WT_CA_O   = 14 * MB;      // 2
constexpr size_t WT_FFN_IN = 16 * MB;      // 8
constexpr size_t WT_FFN_OUT= 24 * MB;      // 8
constexpr size_t ENC_BF    = 32 * MB;      // 8
constexpr size_t XLN       = 40 * MB;      // 8
constexpr size_t QH        = 48 * MB;      // 8
constexpr size_t KT        = 56 * MB;      // 8
constexpr size_t VT        = 64 * MB;      // 8
constexpr size_t CTX       = 72 * MB;      // 8
constexpr size_t HBUF      = 80 * MB;      // 16 (fp32 residual spine)
constexpr size_t SP0       = 96 * MB;      // 16 fp32 partial 0
constexpr size_t SP1       = 112 * MB;     // 16 fp32 partial 1
constexpr size_t FFN_MID   = 128 * MB;     // 32 bf16 [4096,4096]
// total 160 MB

extern "C" void kernel_launch(void* const* d_in, const int* in_sizes, int n_in,
                              void* d_out, int out_size, void* d_ws, size_t ws_size,
                              hipStream_t stream) {
  const float* hidden   = (const float*)d_in[0];
  const float* enc      = (const float*)d_in[1];
  const float* encm     = (const float*)d_in[2];
  const float* ln1w = (const float*)d_in[4],  *ln1b = (const float*)d_in[5];
  const float* qkv_w = (const float*)d_in[6], *qkv_b = (const float*)d_in[7];
  const float* attn_o_w = (const float*)d_in[8], *attn_o_b = (const float*)d_in[9];
  const float* ln2w = (const float*)d_in[10], *ln2b = (const float*)d_in[11];
  const float* q_w = (const float*)d_in[12],  *q_b = (const float*)d_in[13];
  const float* kv_w = (const float*)d_in[14], *kv_b = (const float*)d_in[15];
  const float* ca_o_w = (const float*)d_in[16], *ca_o_b = (const float*)d_in[17];
  const float* ln3w = (const float*)d_in[18], *ln3b = (const float*)d_in[19];
  const float* ffn_in_w = (const float*)d_in[20], *ffn_in_b = (const float*)d_in[21];
  const float* ffn_out_w = (const float*)d_in[22], *ffn_out_b = (const float*)d_in[23];

  char* ws = (char*)d_ws;
  u16* wt_qkv    = (u16*)(ws + WT_QKV);
  u16* wt_attn_o = (u16*)(ws + WT_ATTN_O);
  u16* wt_q      = (u16*)(ws + WT_Q);
  u16* wt_kv     = (u16*)(ws + WT_KV);
  u16* wt_ca_o   = (u16*)(ws + WT_CA_O);
  u16* wt_ffn_in = (u16*)(ws + WT_FFN_IN);
  u16* wt_ffn_out= (u16*)(ws + WT_FFN_OUT);
  u16* enc_bf = (u16*)(ws + ENC_BF);
  u16* xln    = (u16*)(ws + XLN);
  u16* qh     = (u16*)(ws + QH);
  u16* kt     = (u16*)(ws + KT);
  u16* vt     = (u16*)(ws + VT);
  u16* ctx    = (u16*)(ws + CTX);
  float* hF   = (float*)(ws + HBUF);
  float* sp0  = (float*)(ws + SP0);
  float* sp1  = (float*)(ws + SP1);
  u16* ffn_mid = (u16*)(ws + FFN_MID);

  // ---- prep: all weight transposes + enc cvt + LN1, one launch ----
  PrepArgs pa;
  pa.w[0] = qkv_w;    pa.wt[0] = wt_qkv;     pa.K[0] = 1024; pa.N[0] = 3072; pa.cum[0] = 3072;
  pa.w[1] = attn_o_w; pa.wt[1] = wt_attn_o;  pa.K[1] = 1024; pa.N[1] = 1024; pa.cum[1] = 4096;
  pa.w[2] = q_w;      pa.wt[2] = wt_q;       pa.K[2] = 1024; pa.N[2] = 1024; pa.cum[2] = 5120;
  pa.w[3] = kv_w;     pa.wt[3] = wt_kv;      pa.K[3] = 1024; pa.N[3] = 2048; pa.cum[3] = 7168;
  pa.w[4] = ca_o_w;   pa.wt[4] = wt_ca_o;    pa.K[4] = 1024; pa.N[4] = 1024; pa.cum[4] = 8192;
  pa.w[5] = ffn_in_w; pa.wt[5] = wt_ffn_in;  pa.K[5] = 1024; pa.N[5] = 4096; pa.cum[5] = 12288;
  pa.w[6] = ffn_out_w;pa.wt[6] = wt_ffn_out; pa.K[6] = 4096; pa.N[6] = 1024; pa.cum[6] = 16384;
  pa.enc = enc; pa.enc_bf = enc_bf;
  pa.hid = hidden; pa.ln1w = ln1w; pa.ln1b = ln1b; pa.xln = xln;
  prep_kernel<<<24576, 256, 0, stream>>>(pa);

  // ---- self-attention ----
  gemm_big<256, 1><<<dim3(12, 16), 512, 0, stream>>>(xln, wt_qkv, qkv_b, qh, kt, vt, 3072, 1024);
  flash_attn<<<dim3(8, 64), 256, 0, stream>>>(qh, kt, vt, nullptr, ctx, 1);
  gemm_splitk<<<dim3(8, 32, 2), 256, 0, stream>>>(ctx, wt_attn_o, sp0, 1024, 512);
  ln_red_kernel<<<4096, 256, 0, stream>>>(sp0, sp1, attn_o_b, hidden, ln2w, ln2b, hF, xln);

  // ---- cross-attention ----
  gemm_splitk<<<dim3(8, 32, 2), 256, 0, stream>>>(xln, wt_q, sp0, 1024, 512);
  reduce_q_kernel<<<4096, 256, 0, stream>>>(sp0, sp1, q_b, qh);
  gemm_big<128, 3><<<dim3(8, 32), 512, 0, stream>>>(enc_bf, wt_kv, kv_b, nullptr, kt, vt, 2048, 1024);
  flash_attn<<<dim3(8, 64), 256, 0, stream>>>(qh, kt, vt, encm, ctx, 0);
  gemm_splitk<<<dim3(8, 32, 2), 256, 0, stream>>>(ctx, wt_ca_o, sp0, 1024, 512);
  ln_red_kernel<<<4096, 256, 0, stream>>>(sp0, sp1, ca_o_b, hF, ln3w, ln3b, hF, xln);

  // ---- FFN ----
  gemm_big<256, 0><<<dim3(16, 16), 512, 0, stream>>>(xln, wt_ffn_in, ffn_in_b, ffn_mid, nullptr, nullptr, 4096, 1024);
  gemm_splitk<<<dim3(8, 32, 2), 256, 0, stream>>>(ffn_mid, wt_ffn_out, sp0, 4096, 2048);
  reduce_out_kernel<<<4096, 256, 0, stream>>>(sp0, sp1, ffn_out_b, hF, (float*)d_out);
}

// Round 2
// 555.442 us; speedup vs baseline: 1.1041x; 1.0460x over previous
//
#include <hip/hip_runtime.h>
#include <cstdint>
#include <cstddef>

typedef unsigned short u16;
typedef __bf16 bf16x8 __attribute__((ext_vector_type(8)));
typedef float f32x4 __attribute__((ext_vector_type(4)));

// ---------- helpers ----------
__device__ __forceinline__ u16 f2bf(float f) {            // round-to-nearest-even
  unsigned u = __float_as_uint(f);
  u += 0x7fffu + ((u >> 16) & 1u);
  return (u16)(u >> 16);
}

__device__ __forceinline__ float block_sum(float v, float* sbuf, int tid) {
#pragma unroll
  for (int off = 1; off < 64; off <<= 1) v += __shfl_xor(v, off, 64);
  if ((tid & 63) == 0) sbuf[tid >> 6] = v;
  __syncthreads();
  v = sbuf[0] + sbuf[1] + sbuf[2] + sbuf[3];
  __syncthreads();
  return v;
}

// async global->LDS, 16B per lane; LDS dest = wave-uniform base + lane*16.
__device__ __forceinline__ void gld16(const void* g, void* l) {
  __builtin_amdgcn_global_load_lds((const __attribute__((address_space(1))) void*)g,
                                   (__attribute__((address_space(3))) void*)l,
                                   16, 0, 0);
}

// Tiled K layout: kt[z][tile][c=d/8][t=0..127][j=d%8]  (16KB/tile, MFMA B-frag image)
// Tiled V layout: vt[z][tile][tc=t/8][d=0..63][j=t%8]  (16KB/tile)

// =======================================================================
// Big-tile GEMM machinery: BMx256 tile, BK=64, 512 threads (8 waves 2Mx4N),
// 2-phase double-buffer, counted vmcnt, raw s_barrier.
// LDS XOR swizzle both-sides: linear gld16 dest + inverse-swizzled GLOBAL
// source (chunk ^= row&7) + swizzled ds_read_b128.
// Bijective XCD swizzle with sid-linear (bx-fastest) order -> each XCD owns a
// contiguous m-panel (A stays L2-resident; B shared via L3).
// =======================================================================

#define BIG_PREAMBLE(BM, Kdim, KB)                                               \
  constexpr int NQA = (BM) / 64;                                                 \
  constexpr int IF  = (BM) / 32;                                                 \
  const int tid = threadIdx.x;                                                   \
  const int lane = tid & 63, wave = tid >> 6;                                    \
  const int l15 = lane & 15, g = (lane >> 4) & 3;                                \
  const int wr = (wave >> 2) * ((BM) / 2), wc = (wave & 3) * 64;                 \
  const int gx = gridDim.x;                                                      \
  const int nwg = gx * gridDim.y;                                                \
  const int id = blockIdx.y * gx + blockIdx.x;                                   \
  const int qq = nwg >> 3, rr = nwg & 7;                                         \
  const int xcd = id & 7, slot = id >> 3;                                        \
  const int sid = (xcd < rr ? xcd * (qq + 1) : rr * (qq + 1) + (xcd - rr) * qq) + slot; \
  const int bx = sid % gx, by = sid / gx;                                        \
  const int m0 = by * (BM), n0 = bx * 256;                                       \
  size_t aoff[NQA]; int adst[NQA];                                               \
  size_t boff[4];   int bdst[4];                                                 \
  _Pragma("unroll")                                                              \
  for (int q = 0; q < NQA; ++q) {                                                \
    const int c = tid + q * 512, row = c >> 3, ch = (c & 7) ^ (row & 7);         \
    aoff[q] = (size_t)(m0 + row) * (Kdim) + ch * 8 + (KB);                       \
    adst[q] = c * 8;                                                             \
  }                                                                              \
  _Pragma("unroll")                                                              \
  for (int q = 0; q < 4; ++q) {                                                  \
    const int c = tid + q * 512, row = c >> 3, ch = (c & 7) ^ (row & 7);         \
    boff[q] = (size_t)(n0 + row) * (Kdim) + ch * 8 + (KB);                       \
    bdst[q] = c * 8;                                                             \
  }

#define BIG_STAGE(BM, kk, buf)                                                   \
  {                                                                              \
    _Pragma("unroll")                                                            \
    for (int q = 0; q < NQA; ++q) gld16(A + aoff[q] + (kk), As + (buf) * ((BM) * 64) + adst[q]); \
    _Pragma("unroll")                                                            \
    for (int q = 0; q < 4; ++q)  gld16(B + boff[q] + (kk), Bs + (buf) * 16384 + bdst[q]); \
  }

#define BIG_COMPUTE(BM, buf)                                                     \
  {                                                                              \
    _Pragma("unroll")                                                            \
    for (int ks = 0; ks < 2; ++ks) {                                             \
      const int chR = (((ks * 4 + g) ^ (l15 & 7)) * 8);                          \
      bf16x8 af[IF], bg[4];                                                      \
      _Pragma("unroll")                                                          \
      for (int i = 0; i < IF; ++i)                                               \
        af[i] = *(const bf16x8*)(As + (buf) * ((BM) * 64) + (wr + i * 16 + l15) * 64 + chR); \
      _Pragma("unroll")                                                          \
      for (int j = 0; j < 4; ++j)                                                \
        bg[j] = *(const bf16x8*)(Bs + (buf) * 16384 + (wc + j * 16 + l15) * 64 + chR); \
      _Pragma("unroll")                                                          \
      for (int i = 0; i < IF; ++i)                                               \
        _Pragma("unroll")                                                        \
        for (int j = 0; j < 4; ++j)                                              \
          acc[i][j] = __builtin_amdgcn_mfma_f32_16x16x32_bf16(af[i], bg[j], acc[i][j], 0, 0, 0); \
    }                                                                            \
  }

// vmcnt(N): N = loads issued per stage (NQA+4) -> previous stage fully landed.
#define BIG_WAIT_PREV(BM)                                                        \
  if constexpr ((BM) == 256)      asm volatile("s_waitcnt vmcnt(8)\ns_barrier" ::: "memory"); \
  else if constexpr ((BM) == 128) asm volatile("s_waitcnt vmcnt(6)\ns_barrier" ::: "memory"); \
  else                            asm volatile("s_waitcnt vmcnt(5)\ns_barrier" ::: "memory");

#define BIG_KLOOP(BM, NT)                                                        \
  f32x4 acc[IF][4] = {};                                                         \
  BIG_STAGE(BM, 0, 0)                                                            \
  int cur = 0;                                                                   \
  for (int t = 0; t < (NT) - 1; ++t) {                                           \
    BIG_STAGE(BM, (t + 1) * 64, cur ^ 1)                                         \
    BIG_WAIT_PREV(BM)                                                            \
    BIG_COMPUTE(BM, cur)                                                         \
    asm volatile("s_waitcnt lgkmcnt(0)\ns_barrier" ::: "memory");                \
    cur ^= 1;                                                                    \
  }                                                                              \
  asm volatile("s_waitcnt vmcnt(0)\ns_barrier" ::: "memory");                    \
  BIG_COMPUTE(BM, cur)

// ---------- big-tile GEMM with bf16 epilogues ----------
// MODE 0: bias+GELU -> bf16 out0[gm*N+col]
// MODE 1: qkv scatter -> qh(out0, *0.125), kt(out1), vt(out2)
// MODE 3: kv scatter  -> kt(out1), vt(out2)
template<int BM, int MODE>
__global__ __launch_bounds__(512, 2) void gemm_big(
    const u16* __restrict__ A, const u16* __restrict__ B,
    const float* __restrict__ bias,
    u16* __restrict__ out0, u16* __restrict__ out1, u16* __restrict__ out2,
    int N, int K)
{
  __shared__ __align__(16) u16 As[2 * BM * 64];
  __shared__ __align__(16) u16 Bs[2 * 256 * 64];
  BIG_PREAMBLE(BM, K, 0)
  const int NT = K >> 6;
  BIG_KLOOP(BM, NT)

  if constexpr (MODE == 0) {
#pragma unroll
    for (int i = 0; i < IF; ++i) {
#pragma unroll
      for (int j = 0; j < 4; ++j) {
        const int col = n0 + wc + j * 16 + l15;
        const float bs = bias[col];
#pragma unroll
        for (int r = 0; r < 4; ++r) {
          const int gm = m0 + wr + i * 16 + g * 4 + r;
          float v = acc[i][j][r] + bs;
          v = 0.5f * v * (1.0f + erff(v * 0.70710678118654752f));
          out0[(size_t)gm * N + col] = f2bf(v);
        }
      }
    }
  } else {
#pragma unroll
    for (int i = 0; i < IF; ++i) {
#pragma unroll
      for (int j = 0; j < 4; ++j) {
        const int col = n0 + wc + j * 16 + l15;
        const int sec = (n0 + wc + j * 16) >> 10;          // wave-uniform section
        const int tgt = (MODE == 1) ? sec : sec + 1;
        const float bs = bias[col];
#pragma unroll
        for (int r = 0; r < 4; ++r) {
          const int gm = m0 + wr + i * 16 + g * 4 + r;
          const float v = acc[i][j][r] + bs;
          const int cl = col & 1023, h = cl >> 6, d = cl & 63;
          const int z = (gm >> 10) * 16 + h, s = gm & 1023;
          if (tgt == 0)
            out0[((size_t)z * 1024 + s) * 64 + d] = f2bf(v * 0.125f);
          else if (tgt == 1)
            out1[((((size_t)z * 8 + (s >> 7)) * 8 + (d >> 3)) * 128 + (s & 127)) * 8 + (d & 7)] = f2bf(v);
          else
            out2[((size_t)z * 8 + (s >> 7)) * 8192 + (((s >> 3) & 15) * 64 + d) * 8 + (s & 7)] = f2bf(v);
        }
      }
    }
  }
}

// ---------- big-tile GEMM, fp32 partial out over K-range (N=1024) ----------
// z=1 (Klen==K): direct full-K fp32 result (no split-K reduction needed).
// z=2: split-K partials at part + z*16MB (ffn_out).
template<int BM>
__global__ __launch_bounds__(512, 2) void gemm_part(
    const u16* __restrict__ A, const u16* __restrict__ B,
    float* __restrict__ part, int K, int Klen)
{
  __shared__ __align__(16) u16 As[2 * BM * 64];
  __shared__ __align__(16) u16 Bs[2 * 256 * 64];
  const int kb = blockIdx.z * Klen;
  float* outP = part + (size_t)blockIdx.z * (4096ULL * 1024);
  BIG_PREAMBLE(BM, K, kb)
  const int NT = Klen >> 6;
  BIG_KLOOP(BM, NT)

#pragma unroll
  for (int i = 0; i < IF; ++i)
#pragma unroll
    for (int j = 0; j < 4; ++j) {
      const int col = n0 + wc + j * 16 + l15;
#pragma unroll
      for (int r = 0; r < 4; ++r) {
        const int gm = m0 + wr + i * 16 + g * 4 + r;
        outP[(size_t)gm * 1024 + col] = acc[i][j][r];
      }
    }
}

// ---------- flash attention v3 (proven) + head-per-XCD swizzle ----------
__global__ __launch_bounds__(256, 2) void flash_attn(
    const u16* __restrict__ qh, const u16* __restrict__ kt, const u16* __restrict__ vt,
    const float* __restrict__ emask, u16* __restrict__ ctx, int causal)
{
  __shared__ __align__(16) u16 sK[8192];
  __shared__ __align__(16) u16 sV[8192];
  __shared__ __align__(16) u16 sP[128 * 72];

  const int tid = threadIdx.x, lane = tid & 63, wave = tid >> 6;
  const int l15 = lane & 15, g = (lane >> 4) & 3;
  const int id = blockIdx.y * 8 + blockIdx.x;
  const int xcd = id & 7, slot = id >> 3;
  const int z = xcd * 8 + (slot >> 3), b = z >> 4, h = z & 15;
  const int m0 = (slot & 7) * 128;
  const int r0 = wave * 32;

  bf16x8 qf[2][2];
  {
    const u16* qz = qh + ((size_t)z * 1024 + m0 + r0 + l15) * 64 + g * 8;
#pragma unroll
    for (int i2 = 0; i2 < 2; ++i2)
#pragma unroll
      for (int kc = 0; kc < 2; ++kc)
        qf[i2][kc] = *(const bf16x8*)(qz + (size_t)i2 * 16 * 64 + kc * 32);
  }

  float m_i[2][4], l_i[2][4];
#pragma unroll
  for (int i2 = 0; i2 < 2; ++i2)
#pragma unroll
    for (int r = 0; r < 4; ++r) { m_i[i2][r] = -1.0e30f; l_i[i2][r] = 0.0f; }

  f32x4 o[2][4] = {};
  const int tmax = causal ? m0 : 896;

  for (int t0 = 0; t0 <= tmax; t0 += 128) {
    const u16* ktile = kt + ((size_t)z * 8 + (t0 >> 7)) * 8192;
    const u16* vtile = vt + ((size_t)z * 8 + (t0 >> 7)) * 8192;
    __syncthreads();
#pragma unroll
    for (int i = 0; i < 4; ++i) {
      const int off = (wave * 4 + i) * 512 + lane * 8;
      gld16(ktile + off, sK + off);
      gld16(vtile + off, sV + off);
    }
    __syncthreads();

#pragma unroll
    for (int ci = 0; ci < 2; ++ci) {
      if (causal && t0 == m0 && ci * 64 > r0 + 31) continue;

      f32x4 sa[2][4] = {};
#pragma unroll
      for (int kc = 0; kc < 2; ++kc) {
        bf16x8 bg[4];
#pragma unroll
        for (int jn = 0; jn < 4; ++jn)
          bg[jn] = *(const bf16x8*)(sK + ((kc * 4 + g) * 128 + ci * 64 + jn * 16 + l15) * 8);
#pragma unroll
        for (int i2 = 0; i2 < 2; ++i2)
#pragma unroll
          for (int jn = 0; jn < 4; ++jn)
            sa[i2][jn] = __builtin_amdgcn_mfma_f32_16x16x32_bf16(qf[i2][kc], bg[jn], sa[i2][jn], 0, 0, 0);
      }

      if (causal) {
        if (t0 == m0 && ci * 64 + 63 > r0) {
#pragma unroll
          for (int i2 = 0; i2 < 2; ++i2)
#pragma unroll
            for (int jn = 0; jn < 4; ++jn) {
              const int col = ci * 64 + jn * 16 + l15;
#pragma unroll
              for (int r = 0; r < 4; ++r) {
                const int row = r0 + i2 * 16 + g * 4 + r;
                if (col > row) sa[i2][jn][r] = -3.0e38f;
              }
            }
        }
      } else {
#pragma unroll
        for (int jn = 0; jn < 4; ++jn) {
          const float mv = emask[(size_t)b * 1024 + t0 + ci * 64 + jn * 16 + l15];
#pragma unroll
          for (int i2 = 0; i2 < 2; ++i2)
#pragma unroll
            for (int r = 0; r < 4; ++r) sa[i2][jn][r] += mv;
        }
      }

      float alpha[2][4];
#pragma unroll
      for (int i2 = 0; i2 < 2; ++i2)
#pragma unroll
        for (int r = 0; r < 4; ++r) {
          const int rowl = r0 + i2 * 16 + g * 4 + r;
          float v = fmaxf(fmaxf(sa[i2][0][r], sa[i2][1][r]), fmaxf(sa[i2][2][r], sa[i2][3][r]));
          v = fmaxf(v, __shfl_xor(v, 1, 64));
          v = fmaxf(v, __shfl_xor(v, 2, 64));
          v = fmaxf(v, __shfl_xor(v, 4, 64));
          v = fmaxf(v, __shfl_xor(v, 8, 64));
          const float mo = m_i[i2][r];
          const float mn = fmaxf(mo, v);
          m_i[i2][r] = mn;
          alpha[i2][r] = __expf(mo - mn);
          float s = 0.0f;
#pragma unroll
          for (int jn = 0; jn < 4; ++jn) {
            const float p = __expf(sa[i2][jn][r] - mn);
            s += p;
            sP[rowl * 72 + jn * 16 + l15] = f2bf(p);
          }
          s += __shfl_xor(s, 1, 64);
          s += __shfl_xor(s, 2, 64);
          s += __shfl_xor(s, 4, 64);
          s += __shfl_xor(s, 8, 64);
          l_i[i2][r] = alpha[i2][r] * l_i[i2][r] + s;
        }

#pragma unroll
      for (int i2 = 0; i2 < 2; ++i2)
#pragma unroll
        for (int jn = 0; jn < 4; ++jn)
#pragma unroll
          for (int r = 0; r < 4; ++r)
            o[i2][jn][r] *= alpha[i2][r];

      asm volatile("s_waitcnt lgkmcnt(0)" ::: "memory");
#pragma unroll
      for (int kc2 = 0; kc2 < 2; ++kc2) {
        bf16x8 pa[2], vb[4];
#pragma unroll
        for (int i2 = 0; i2 < 2; ++i2)
          pa[i2] = *(const bf16x8*)(sP + (r0 + i2 * 16 + l15) * 72 + kc2 * 32 + g * 8);
#pragma unroll
        for (int jn = 0; jn < 4; ++jn)
          vb[jn] = *(const bf16x8*)(sV + ((ci * 8 + kc2 * 4 + g) * 64 + jn * 16 + l15) * 8);
#pragma unroll
        for (int i2 = 0; i2 < 2; ++i2)
#pragma unroll
          for (int jn = 0; jn < 4; ++jn)
            o[i2][jn] = __builtin_amdgcn_mfma_f32_16x16x32_bf16(pa[i2], vb[jn], o[i2][jn], 0, 0, 0);
      }
    }
  }

#pragma unroll
  for (int i2 = 0; i2 < 2; ++i2)
#pragma unroll
    for (int r = 0; r < 4; ++r) {
      const float inv = 1.0f / l_i[i2][r];
      const size_t base = ((size_t)(b * 1024 + m0 + r0 + i2 * 16 + g * 4 + r)) * 1024 + h * 64;
#pragma unroll
      for (int jn = 0; jn < 4; ++jn)
        ctx[base + jn * 16 + l15] = f2bf(o[i2][jn][r] * inv);
    }
}

// ---------- mega prep: 7 weight transposes + enc cvt + LN1 in one launch ----------
struct PrepArgs {
  const float* w[7]; u16* wt[7]; int K[7]; int N[7]; int cum[7];
  const float* enc; u16* enc_bf;
  const float* hid; const float* ln1w; const float* ln1b; u16* xln;
};
__global__ __launch_bounds__(256) void prep_kernel(PrepArgs a) {
  __shared__ float t[32][33];
  __shared__ float sbuf[4];
  const int bb = blockIdx.x, tid = threadIdx.x;
  if (bb < 16384) {
    int wi = 0;
#pragma unroll
    for (int i = 0; i < 7; ++i) if (bb >= a.cum[i]) wi = i + 1; else break;
    const int base = wi ? a.cum[wi - 1] : 0;
    const int tileIdx = bb - base;
    const int Kd = a.K[wi], Nd = a.N[wi], nx = Nd >> 5;
    const int n0 = (tileIdx % nx) * 32, k0 = (tileIdx / nx) * 32;
    const float* w = a.w[wi]; u16* wt = a.wt[wi];
    const int tx = tid & 31, ty = tid >> 5;
#pragma unroll
    for (int r = ty; r < 32; r += 8) t[r][tx] = w[(size_t)(k0 + r) * Nd + n0 + tx];
    __syncthreads();
#pragma unroll
    for (int r = ty; r < 32; r += 8) wt[(size_t)(n0 + r) * Kd + k0 + tx] = f2bf(t[tx][r]);
  } else if (bb < 20480) {
    const size_t i = ((size_t)(bb - 16384) * 256 + tid) * 4;
    const float4 v = *(const float4*)(a.enc + i);
    ushort4 o; o.x = f2bf(v.x); o.y = f2bf(v.y); o.z = f2bf(v.z); o.w = f2bf(v.w);
    *(ushort4*)(a.enc_bf + i) = o;
  } else {
    const int row = bb - 20480;
    const float4 v = *(const float4*)(a.hid + (size_t)row * 1024 + tid * 4);
    float s = block_sum(v.x + v.y + v.z + v.w, sbuf, tid);
    const float u = s * (1.0f / 1024.0f);
    const float d0 = v.x - u, d1 = v.y - u, d2 = v.z - u, d3 = v.w - u;
    float sq = block_sum(d0 * d0 + d1 * d1 + d2 * d2 + d3 * d3, sbuf, tid);
    const float rstd = rsqrtf(sq * (1.0f / 1024.0f) + 1e-12f);
    const int c = tid * 4;
    ushort4 o;
    o.x = f2bf(a.ln1w[c + 0] * d0 * rstd + a.ln1b[c + 0]);
    o.y = f2bf(a.ln1w[c + 1] * d1 * rstd + a.ln1b[c + 1]);
    o.z = f2bf(a.ln1w[c + 2] * d2 * rstd + a.ln1b[c + 2]);
    o.w = f2bf(a.ln1w[c + 3] * d3 * rstd + a.ln1b[c + 3]);
    *(ushort4*)(a.xln + (size_t)row * 1024 + c) = o;
  }
}

// ---------- reducers ----------
// 1-way: full-K fp32 result + bias + residual -> residual spine + LN -> bf16
__global__ __launch_bounds__(256) void ln_red1_kernel(
    const float* __restrict__ p0,
    const float* __restrict__ bias, const float* __restrict__ res,
    const float* __restrict__ w, const float* __restrict__ b,
    float* __restrict__ hOut, u16* __restrict__ xln)
{
  __shared__ float sbuf[4];
  const int row = blockIdx.x, tid = threadIdx.x;
  const size_t off = (size_t)row * 1024 + tid * 4;
  const int c = tid * 4;
  const float4 a0 = *(const float4*)(p0 + off);
  const float4 bs = *(const float4*)(bias + c);
  const float4 rs = *(const float4*)(res + off);
  float4 v;
  v.x = a0.x + bs.x + rs.x;
  v.y = a0.y + bs.y + rs.y;
  v.z = a0.z + bs.z + rs.z;
  v.w = a0.w + bs.w + rs.w;
  *(float4*)(hOut + off) = v;
  float s = block_sum(v.x + v.y + v.z + v.w, sbuf, tid);
  const float u = s * (1.0f / 1024.0f);
  const float d0 = v.x - u, d1 = v.y - u, d2 = v.z - u, d3 = v.w - u;
  float sq = block_sum(d0 * d0 + d1 * d1 + d2 * d2 + d3 * d3, sbuf, tid);
  const float rstd = rsqrtf(sq * (1.0f / 1024.0f) + 1e-12f);
  ushort4 o;
  o.x = f2bf(w[c + 0] * d0 * rstd + b[c + 0]);
  o.y = f2bf(w[c + 1] * d1 * rstd + b[c + 1]);
  o.z = f2bf(w[c + 2] * d2 * rstd + b[c + 2]);
  o.w = f2bf(w[c + 3] * d3 * rstd + b[c + 3]);
  *(ushort4*)(xln + off) = o;
}

__global__ __launch_bounds__(256) void reduce_q1_kernel(
    const float* __restrict__ p0,
    const float* __restrict__ bias, u16* __restrict__ qh)
{
  const int m = blockIdx.x, tid = threadIdx.x;
  const size_t off = (size_t)m * 1024 + tid * 4;
  const int n = tid * 4, h = n >> 6, d = n & 63;
  const int b = m >> 10, s = m & 1023;
  const float4 a0 = *(const float4*)(p0 + off);
  const float4 bs = *(const float4*)(bias + n);
  ushort4 o;
  o.x = f2bf((a0.x + bs.x) * 0.125f);
  o.y = f2bf((a0.y + bs.y) * 0.125f);
  o.z = f2bf((a0.z + bs.z) * 0.125f);
  o.w = f2bf((a0.w + bs.w) * 0.125f);
  *(ushort4*)(qh + ((size_t)((b * 16 + h) * 1024 + s)) * 64 + d) = o;
}

// 2-way: split-K sum + bias + residual -> fp32 out (final layer output)
__global__ __launch_bounds__(256) void reduce_out_kernel(
    const float* __restrict__ p0, const float* __restrict__ p1,
    const float* __restrict__ bias, const float* __restrict__ res,
    float* __restrict__ out)
{
  const int m = blockIdx.x, tid = threadIdx.x;
  const size_t off = (size_t)m * 1024 + tid * 4;
  const int c = tid * 4;
  const float4 a0 = *(const float4*)(p0 + off);
  const float4 a1 = *(const float4*)(p1 + off);
  const float4 bs = *(const float4*)(bias + c);
  const float4 rs = *(const float4*)(res + off);
  float4 v;
  v.x = a0.x + a1.x + bs.x + rs.x;
  v.y = a0.y + a1.y + bs.y + rs.y;
  v.z = a0.z + a1.z + bs.z + rs.z;
  v.w = a0.w + a1.w + bs.w + rs.w;
  *(float4*)(out + off) = v;
}

// ---------- workspace layout (bytes) ----------
constexpr size_t MB = 1024ULL * 1024;
constexpr size_t WT_QKV    = 0;            // 6 MB
constexpr size_t WT_ATTN_O = 6 * MB;       // 2
constexpr size_t WT_Q      = 8 * MB;       // 2
constexpr size_t WT_KV     = 10 * MB;      // 4
constexpr size_t WT_CA_O   = 14 * MB;      // 2
constexpr size_t WT_FFN_IN = 16 * MB;      // 8
constexpr size_t WT_FFN_OUT= 24 * MB;      // 8
constexpr size_t ENC_BF    = 32 * MB;      // 8
constexpr size_t XLN       = 40 * MB;      // 8
constexpr size_t QH        = 48 * MB;      // 8
constexpr size_t KT        = 56 * MB;      // 8
constexpr size_t VT        = 64 * MB;      // 8
constexpr size_t CTX       = 72 * MB;      // 8
constexpr size_t HBUF      = 80 * MB;      // 16 (fp32 residual spine)
constexpr size_t SP0       = 96 * MB;      // 16 fp32 partial 0
constexpr size_t SP1       = 112 * MB;     // 16 fp32 partial 1 (z=1 slab of ffn split-K)
constexpr size_t FFN_MID   = 128 * MB;     // 32 bf16 [4096,4096]
// total 160 MB

extern "C" void kernel_launch(void* const* d_in, const int* in_sizes, int n_in,
                              void* d_out, int out_size, void* d_ws, size_t ws_size,
                              hipStream_t stream) {
  const float* hidden   = (const float*)d_in[0];
  const float* enc      = (const float*)d_in[1];
  const float* encm     = (const float*)d_in[2];
  const float* ln1w = (const float*)d_in[4],  *ln1b = (const float*)d_in[5];
  const float* qkv_w = (const float*)d_in[6], *qkv_b = (const float*)d_in[7];
  const float* attn_o_w = (const float*)d_in[8], *attn_o_b = (const float*)d_in[9];
  const float* ln2w = (const float*)d_in[10], *ln2b = (const float*)d_in[11];
  const float* q_w = (const float*)d_in[12],  *q_b = (const float*)d_in[13];
  const float* kv_w = (const float*)d_in[14], *kv_b = (const float*)d_in[15];
  const float* ca_o_w = (const float*)d_in[16], *ca_o_b = (const float*)d_in[17];
  const float* ln3w = (const float*)d_in[18], *ln3b = (const float*)d_in[19];
  const float* ffn_in_w = (const float*)d_in[20], *ffn_in_b = (const float*)d_in[21];
  const float* ffn_out_w = (const float*)d_in[22], *ffn_out_b = (const float*)d_in[23];

  char* ws = (char*)d_ws;
  u16* wt_qkv    = (u16*)(ws + WT_QKV);
  u16* wt_attn_o = (u16*)(ws + WT_ATTN_O);
  u16* wt_q      = (u16*)(ws + WT_Q);
  u16* wt_kv     = (u16*)(ws + WT_KV);
  u16* wt_ca_o   = (u16*)(ws + WT_CA_O);
  u16* wt_ffn_in = (u16*)(ws + WT_FFN_IN);
  u16* wt_ffn_out= (u16*)(ws + WT_FFN_OUT);
  u16* enc_bf = (u16*)(ws + ENC_BF);
  u16* xln    = (u16*)(ws + XLN);
  u16* qh     = (u16*)(ws + QH);
  u16* kt     = (u16*)(ws + KT);
  u16* vt     = (u16*)(ws + VT);
  u16* ctx    = (u16*)(ws + CTX);
  float* hF   = (float*)(ws + HBUF);
  float* sp0  = (float*)(ws + SP0);
  float* sp1  = (float*)(ws + SP1);
  u16* ffn_mid = (u16*)(ws + FFN_MID);

  // ---- prep: all weight transposes + enc cvt + LN1, one launch ----
  PrepArgs pa;
  pa.w[0] = qkv_w;    pa.wt[0] = wt_qkv;     pa.K[0] = 1024; pa.N[0] = 3072; pa.cum[0] = 3072;
  pa.w[1] = attn_o_w; pa.wt[1] = wt_attn_o;  pa.K[1] = 1024; pa.N[1] = 1024; pa.cum[1] = 4096;
  pa.w[2] = q_w;      pa.wt[2] = wt_q;       pa.K[2] = 1024; pa.N[2] = 1024; pa.cum[2] = 5120;
  pa.w[3] = kv_w;     pa.wt[3] = wt_kv;      pa.K[3] = 1024; pa.N[3] = 2048; pa.cum[3] = 7168;
  pa.w[4] = ca_o_w;   pa.wt[4] = wt_ca_o;    pa.K[4] = 1024; pa.N[4] = 1024; pa.cum[4] = 8192;
  pa.w[5] = ffn_in_w; pa.wt[5] = wt_ffn_in;  pa.K[5] = 1024; pa.N[5] = 4096; pa.cum[5] = 12288;
  pa.w[6] = ffn_out_w;pa.wt[6] = wt_ffn_out; pa.K[6] = 4096; pa.N[6] = 1024; pa.cum[6] = 16384;
  pa.enc = enc; pa.enc_bf = enc_bf;
  pa.hid = hidden; pa.ln1w = ln1w; pa.ln1b = ln1b; pa.xln = xln;
  prep_kernel<<<24576, 256, 0, stream>>>(pa);

  // ---- self-attention ----
  gemm_big<256, 1><<<dim3(12, 16), 512, 0, stream>>>(xln, wt_qkv, qkv_b, qh, kt, vt, 3072, 1024);
  flash_attn<<<dim3(8, 64), 256, 0, stream>>>(qh, kt, vt, nullptr, ctx, 1);
  gemm_part<64><<<dim3(4, 64, 1), 512, 0, stream>>>(ctx, wt_attn_o, sp0, 1024, 1024);
  ln_red1_kernel<<<4096, 256, 0, stream>>>(sp0, attn_o_b, hidden, ln2w, ln2b, hF, xln);

  // ---- cross-attention ----
  gemm_part<64><<<dim3(4, 64, 1), 512, 0, stream>>>(xln, wt_q, sp0, 1024, 1024);
  reduce_q1_kernel<<<4096, 256, 0, stream>>>(sp0, q_b, qh);
  gemm_big<128, 3><<<dim3(8, 32), 512, 0, stream>>>(enc_bf, wt_kv, kv_b, nullptr, kt, vt, 2048, 1024);
  flash_attn<<<dim3(8, 64), 256, 0, stream>>>(qh, kt, vt, encm, ctx, 0);
  gemm_part<64><<<dim3(4, 64, 1), 512, 0, stream>>>(ctx, wt_ca_o, sp0, 1024, 1024);
  ln_red1_kernel<<<4096, 256, 0, stream>>>(sp0, ca_o_b, hF, ln3w, ln3b, hF, xln);

  // ---- FFN ----
  gemm_big<256, 0><<<dim3(16, 16), 512, 0, stream>>>(xln, wt_ffn_in, ffn_in_b, ffn_mid, nullptr, nullptr, 4096, 1024);
  gemm_part<128><<<dim3(4, 32, 2), 512, 0, stream>>>(ffn_mid, wt_ffn_out, sp0, 4096, 2048);
  reduce_out_kernel<<<4096, 256, 0, stream>>>(sp0, sp1, ffn_out_b, hF, (float*)d_out);
}